// Round 9
// baseline (1969.287 us; speedup 1.0000x reference)
//
#include <hip/hip_runtime.h>
#include <cstdint>

#define T_ 4
#define B_ 16
#define N_ 256
#define C_ 512
#define H_ 8
#define HID_ 2048
#define M_ (T_*B_*N_)      // 16384 rows
#define BNP_ (B_*N_)       // 4096 (b,n) pairs

// ---------------------------------------------------------------------------
// fp32 tiled GEMM (R1-verbatim):  Y[M x Nc] = A[M x K] * W[Nc x K]^T + bias
// Used for q, k, f1, f2 paths — MUST stay bit-identical to R1.
// ---------------------------------------------------------------------------
__global__ __launch_bounds__(256)
void gemm_nt(const float* __restrict__ A, const float* __restrict__ W,
             const float* __restrict__ bias, float* __restrict__ Y,
             int Nc, int K) {
  __shared__ float As[16][132];   // [k][row], padded
  __shared__ float Ws[16][132];   // [k][col], padded
  const int tid  = threadIdx.x;
  const int row0 = blockIdx.y * 128;
  const int col0 = blockIdx.x * 128;
  const int tx = tid & 15, ty = tid >> 4;

  float acc[8][8];
  #pragma unroll
  for (int i = 0; i < 8; ++i)
    #pragma unroll
    for (int j = 0; j < 8; ++j) acc[i][j] = 0.f;

  const int ar = tid >> 2;         // 0..63
  const int ac = (tid & 3) << 2;   // 0,4,8,12

  for (int k0 = 0; k0 < K; k0 += 16) {
    __syncthreads();
    #pragma unroll
    for (int i = 0; i < 2; ++i) {
      int r = ar + i * 64;
      float4 a4 = *(const float4*)(A + (size_t)(row0 + r) * K + (k0 + ac));
      As[ac+0][r] = a4.x; As[ac+1][r] = a4.y; As[ac+2][r] = a4.z; As[ac+3][r] = a4.w;
      float4 w4 = *(const float4*)(W + (size_t)(col0 + r) * K + (k0 + ac));
      Ws[ac+0][r] = w4.x; Ws[ac+1][r] = w4.y; Ws[ac+2][r] = w4.z; Ws[ac+3][r] = w4.w;
    }
    __syncthreads();
    #pragma unroll
    for (int kk = 0; kk < 16; ++kk) {
      float a[8], b[8];
      *(float4*)&a[0] = *(const float4*)&As[kk][ty*8];
      *(float4*)&a[4] = *(const float4*)&As[kk][ty*8+4];
      *(float4*)&b[0] = *(const float4*)&Ws[kk][tx*8];
      *(float4*)&b[4] = *(const float4*)&Ws[kk][tx*8+4];
      #pragma unroll
      for (int i = 0; i < 8; ++i)
        #pragma unroll
        for (int j = 0; j < 8; ++j)
          acc[i][j] = fmaf(a[i], b[j], acc[i][j]);
    }
  }
  #pragma unroll
  for (int i = 0; i < 8; ++i) {
    size_t r = (size_t)(row0 + ty*8 + i);
    #pragma unroll
    for (int j4 = 0; j4 < 2; ++j4) {
      int c = col0 + tx*8 + j4*4;
      float4 o4;
      o4.x = acc[i][j4*4+0] + bias[c+0];
      o4.y = acc[i][j4*4+1] + bias[c+1];
      o4.z = acc[i][j4*4+2] + bias[c+2];
      o4.w = acc[i][j4*4+3] + bias[c+3];
      *(float4*)(Y + r * Nc + c) = o4;
    }
  }
}

// ---------------------------------------------------------------------------
// v/p path GEMM: f32 in/out, f64 accumulation (fresh rounding realization).
// BM=BN=64, BK=16, 256 threads, 4x4 f64 micro-tile; LDS stays f32.
// ---------------------------------------------------------------------------
__global__ __launch_bounds__(256)
void gemm_nt_f64acc(const float* __restrict__ A, const float* __restrict__ W,
                    const float* __restrict__ bias, float* __restrict__ Y,
                    int Nc, int K) {
  __shared__ float As[16][68];   // [k][row], padded
  __shared__ float Ws[16][68];   // [k][col], padded
  const int tid  = threadIdx.x;
  const int row0 = blockIdx.y * 64;
  const int col0 = blockIdx.x * 64;
  const int tx = tid & 15, ty = tid >> 4;

  double acc[4][4];
  #pragma unroll
  for (int i = 0; i < 4; ++i)
    #pragma unroll
    for (int j = 0; j < 4; ++j) acc[i][j] = 0.0;

  const int lr = tid >> 2;         // 0..63
  const int lk = (tid & 3) << 2;   // 0,4,8,12

  for (int k0 = 0; k0 < K; k0 += 16) {
    __syncthreads();
    {
      float4 a4 = *(const float4*)(A + (size_t)(row0 + lr) * K + (k0 + lk));
      As[lk+0][lr] = a4.x; As[lk+1][lr] = a4.y; As[lk+2][lr] = a4.z; As[lk+3][lr] = a4.w;
      float4 w4 = *(const float4*)(W + (size_t)(col0 + lr) * K + (k0 + lk));
      Ws[lk+0][lr] = w4.x; Ws[lk+1][lr] = w4.y; Ws[lk+2][lr] = w4.z; Ws[lk+3][lr] = w4.w;
    }
    __syncthreads();
    #pragma unroll
    for (int kk = 0; kk < 16; ++kk) {
      double a[4], b[4];
      #pragma unroll
      for (int i = 0; i < 4; ++i) a[i] = (double)As[kk][ty*4+i];
      #pragma unroll
      for (int j = 0; j < 4; ++j) b[j] = (double)Ws[kk][tx*4+j];
      #pragma unroll
      for (int i = 0; i < 4; ++i)
        #pragma unroll
        for (int j = 0; j < 4; ++j)
          acc[i][j] = fma(a[i], b[j], acc[i][j]);
    }
  }
  #pragma unroll
  for (int i = 0; i < 4; ++i) {
    size_t r = (size_t)(row0 + ty*4 + i);
    int c = col0 + tx*4;
    float4 o4;
    o4.x = (float)(acc[i][0] + (double)bias[c+0]);
    o4.y = (float)(acc[i][1] + (double)bias[c+1]);
    o4.z = (float)(acc[i][2] + (double)bias[c+2]);
    o4.w = (float)(acc[i][3] + (double)bias[c+3]);
    *(float4*)(Y + r * Nc + c) = o4;
  }
}

// ---------------------------------------------------------------------------
// BN stats stage 1 (R1-verbatim)
// ---------------------------------------------------------------------------
__global__ __launch_bounds__(256)
void col_stats_partial(const float* __restrict__ Y, int Nc,
                       float* __restrict__ psum, float* __restrict__ psq) {
  const int r0 = blockIdx.x * 32;
  for (int c = threadIdx.x; c < Nc; c += 256) {
    float s = 0.f, q = 0.f;
    const float* p = Y + (size_t)r0 * Nc + c;
    for (int r = 0; r < 32; ++r) {
      float v = p[(size_t)r * Nc];
      s += v;
      q = fmaf(v, v, q);
    }
    psum[(size_t)blockIdx.x * Nc + c] = s;
    psq [(size_t)blockIdx.x * Nc + c] = q;
  }
}

// stage 2 (R1-verbatim): f32 chp for q/k/f1/f2 paths
__global__ void col_stats_final(const float* __restrict__ psum, const float* __restrict__ psq,
                                int Nc, const float* __restrict__ g, const float* __restrict__ beta,
                                float* __restrict__ chp) {
  int c = blockIdx.x * blockDim.x + threadIdx.x;
  if (c >= Nc) return;
  double s = 0.0, q = 0.0;
  for (int p = 0; p < 512; ++p) {
    s += (double)psum[(size_t)p * Nc + c];
    q += (double)psq [(size_t)p * Nc + c];
  }
  double mean = s / (double)M_;
  double var  = q / (double)M_ - mean * mean;
  float alpha = g[c] / sqrtf((float)var + 1e-5f);
  chp[2*c]   = alpha;
  chp[2*c+1] = fmaf(-(float)mean, alpha, beta[c]);   // beta - mean*alpha
}

// stage 2 for v/p paths: f64 affine params
__global__ void col_stats_final_f64(const float* __restrict__ psum, const float* __restrict__ psq,
                                    int Nc, const float* __restrict__ g, const float* __restrict__ beta,
                                    double* __restrict__ chpd) {
  int c = blockIdx.x * blockDim.x + threadIdx.x;
  if (c >= Nc) return;
  double s = 0.0, q = 0.0;
  for (int p = 0; p < 512; ++p) {
    s += (double)psum[(size_t)p * Nc + c];
    q += (double)psq [(size_t)p * Nc + c];
  }
  double mean = s / (double)M_;
  double var  = q / (double)M_ - mean * mean;
  double alpha = (double)g[c] / sqrt(var + 1e-5);
  chpd[2*c]   = alpha;
  chpd[2*c+1] = (double)beta[c] - mean * alpha;
}

// ---------------------------------------------------------------------------
// BN + LIF masks (R1-verbatim) — q/k decisions, frozen
// ---------------------------------------------------------------------------
__global__ __launch_bounds__(256)
void bnlif_mask(const float* __restrict__ Y, const float* __restrict__ chp,
                unsigned long long* __restrict__ mask) {
  int lane = threadIdx.x & 63;
  int u  = blockIdx.x * 4 + (threadIdx.x >> 6);
  int bn = u >> 3, cg = u & 7;          // cg == head (Dh==64)
  int c  = cg * 64 + lane;
  float alpha = chp[2*c], bb = chp[2*c+1];
  float v = 0.f;
  #pragma unroll
  for (int t = 0; t < 4; ++t) {
    float y  = Y[((size_t)(t * BNP_ + bn)) * C_ + c];
    float uu = fmaf(y, alpha, bb);
    v = v + (uu - v) * 0.5f;            // v += (x - v)/tau, tau=2
    bool sp = (v >= 1.0f);
    unsigned long long m = __ballot(sp);
    if (sp) v = 0.f;                    // hard reset
    if (lane == 0) mask[((size_t)(t * BNP_ + bn)) * H_ + cg] = m;
  }
}

// BN apply (v path), f64 math → f32 out
__global__ void bn_apply_f64(const float* __restrict__ Y, const double* __restrict__ chpd,
                             float* __restrict__ out) {
  const long total4 = (long)M_ * C_ / 4;
  for (long i = (long)blockIdx.x * blockDim.x + threadIdx.x; i < total4;
       i += (long)gridDim.x * blockDim.x) {
    int c4 = (int)(i & (C_/4 - 1)) * 4;
    float4 y = ((const float4*)Y)[i];
    float4 r;
    r.x = (float)fma((double)y.x, chpd[2*(c4+0)], chpd[2*(c4+0)+1]);
    r.y = (float)fma((double)y.y, chpd[2*(c4+1)], chpd[2*(c4+1)+1]);
    r.z = (float)fma((double)y.z, chpd[2*(c4+2)], chpd[2*(c4+2)+1]);
    r.w = (float)fma((double)y.w, chpd[2*(c4+3)], chpd[2*(c4+3)+1]);
    ((float4*)out)[i] = r;
  }
}

// xo = x + BN(Yp), f64 math → f32 out (p path)
__global__ void bn_residual_f64(const float* __restrict__ Y, const double* __restrict__ chpd,
                                const float* __restrict__ x, float* __restrict__ out) {
  const long total4 = (long)M_ * C_ / 4;
  for (long i = (long)blockIdx.x * blockDim.x + threadIdx.x; i < total4;
       i += (long)gridDim.x * blockDim.x) {
    int c4 = (int)(i & (C_/4 - 1)) * 4;
    float4 y = ((const float4*)Y)[i];
    float4 xv = ((const float4*)x)[i];
    float4 r;
    r.x = (float)((double)xv.x + fma((double)y.x, chpd[2*(c4+0)], chpd[2*(c4+0)+1]));
    r.y = (float)((double)xv.y + fma((double)y.y, chpd[2*(c4+1)], chpd[2*(c4+1)+1]));
    r.z = (float)((double)xv.z + fma((double)y.z, chpd[2*(c4+2)], chpd[2*(c4+2)+1]));
    r.w = (float)((double)xv.w + fma((double)y.w, chpd[2*(c4+3)], chpd[2*(c4+3)+1]));
    ((float4*)out)[i] = r;
  }
}

// BN + LIF for f1 (R1-verbatim), spikes in place as 1.0f/0.0f
__global__ __launch_bounds__(256)
void bnlif_inplace(float* __restrict__ Y, const float* __restrict__ chp) {
  int c  = blockIdx.x * 256 + threadIdx.x;   // < 2048
  int bn = blockIdx.y;
  float alpha = chp[2*c], bb = chp[2*c+1];
  float v = 0.f;
  #pragma unroll
  for (int t = 0; t < 4; ++t) {
    size_t idx = ((size_t)(t * BNP_ + bn)) * HID_ + c;
    float uu = fmaf(Y[idx], alpha, bb);
    v = v + (uu - v) * 0.5f;
    bool sp = (v >= 1.f);
    Y[idx] = sp ? 1.f : 0.f;
    if (sp) v = 0.f;
  }
}

// BN + LIF for f2 + final residual (R1-verbatim)
__global__ __launch_bounds__(256)
void bnlif_final(const float* __restrict__ Y, const float* __restrict__ chp,
                 const float* __restrict__ xo, float* __restrict__ out) {
  int c  = blockIdx.x * 256 + threadIdx.x;   // < 512
  int bn = blockIdx.y;
  float alpha = chp[2*c], bb = chp[2*c+1];
  float v = 0.f;
  #pragma unroll
  for (int t = 0; t < 4; ++t) {
    size_t idx = ((size_t)(t * BNP_ + bn)) * C_ + c;
    float uu = fmaf(Y[idx], alpha, bb);
    v = v + (uu - v) * 0.5f;
    bool sp = (v >= 1.f);
    out[idx] = xo[idx] + (sp ? 1.f : 0.f);
    if (sp) v = 0.f;
  }
}

// ---------------------------------------------------------------------------
// Attention: popcount QK (exact); PV accumulated in f64 → f32 o.
// ---------------------------------------------------------------------------
__global__ __launch_bounds__(256)
void attn_kernel_f64(const unsigned long long* __restrict__ qmask,
                     const unsigned long long* __restrict__ kmask,
                     const float* __restrict__ v, float* __restrict__ o) {
  __shared__ unsigned long long km[256];
  __shared__ float vt[256][64];
  int rb  = blockIdx.x & 3;
  int tbh = blockIdx.x >> 2;
  int h   = tbh & 7, tb = tbh >> 3;     // tb = t*16+b
  int tid = threadIdx.x;

  km[tid] = kmask[(size_t)(tb * 256 + tid) * H_ + h];
  const float* vbase = v + (size_t)tb * 256 * C_ + h * 64;
  #pragma unroll
  for (int i = 0; i < 16; ++i) {
    int f = i * 256 + tid;
    int r = f >> 4, c4 = f & 15;
    *(float4*)&vt[r][c4 * 4] = *(const float4*)(vbase + (size_t)r * C_ + c4 * 4);
  }
  int lane = tid & 63, w = tid >> 6;
  int nr = lane & 15, dg = lane >> 4;
  int n  = rb * 64 + w * 16 + nr;
  unsigned long long qm = qmask[(size_t)(tb * 256 + n) * H_ + h];
  __syncthreads();

  double acc[16];
  #pragma unroll
  for (int j = 0; j < 16; ++j) acc[j] = 0.0;

  for (int m = 0; m < 256; ++m) {
    double s = (double)__popcll(qm & km[m]) * 0.125;   // exact
    #pragma unroll
    for (int j = 0; j < 4; ++j) {
      float4 vv = *(const float4*)&vt[m][dg * 16 + j * 4];
      acc[j*4+0] = fma(s, (double)vv.x, acc[j*4+0]);
      acc[j*4+1] = fma(s, (double)vv.y, acc[j*4+1]);
      acc[j*4+2] = fma(s, (double)vv.z, acc[j*4+2]);
      acc[j*4+3] = fma(s, (double)vv.w, acc[j*4+3]);
    }
  }
  float* orow = o + (size_t)(tb * 256 + n) * C_ + h * 64 + dg * 16;
  #pragma unroll
  for (int j = 0; j < 4; ++j)
    *(float4*)(orow + j * 4) = make_float4((float)acc[j*4], (float)acc[j*4+1],
                                           (float)acc[j*4+2], (float)acc[j*4+3]);
}

// ---------------------------------------------------------------------------
extern "C" void kernel_launch(void* const* d_in, const int* in_sizes, int n_in,
                              void* d_out, int out_size, void* d_ws, size_t ws_size,
                              hipStream_t stream) {
  const float* x    = (const float*)d_in[0];
  const float* qw   = (const float*)d_in[2];
  const float* qb   = (const float*)d_in[3];
  const float* qg   = (const float*)d_in[4];
  const float* qbe  = (const float*)d_in[5];
  const float* kw   = (const float*)d_in[6];
  const float* kb   = (const float*)d_in[7];
  const float* kg   = (const float*)d_in[8];
  const float* kbe  = (const float*)d_in[9];
  const float* vw   = (const float*)d_in[10];
  const float* vb   = (const float*)d_in[11];
  const float* vg   = (const float*)d_in[12];
  const float* vbe  = (const float*)d_in[13];
  const float* pw   = (const float*)d_in[14];
  const float* pb   = (const float*)d_in[15];
  const float* pg   = (const float*)d_in[16];
  const float* pbe  = (const float*)d_in[17];
  const float* f1w  = (const float*)d_in[18];
  const float* f1b  = (const float*)d_in[19];
  const float* f1g  = (const float*)d_in[20];
  const float* f1be = (const float*)d_in[21];
  const float* f2w  = (const float*)d_in[22];
  const float* f2b  = (const float*)d_in[23];
  const float* f2g  = (const float*)d_in[24];
  const float* f2be = (const float*)d_in[25];

  char* ws = (char*)d_ws;
  float* bufY = (float*)(ws);                                   // 128 MB (16384x2048 f32)
  float* bufV = (float*)(ws + 134217728ull);                    //  32 MB
  float* bufO = (float*)(ws + 167772160ull);                    //  32 MB (o, then xo)
  unsigned long long* qmask = (unsigned long long*)(ws + 201326592ull);  // 1 MB
  unsigned long long* kmask = (unsigned long long*)(ws + 202375168ull);  // 1 MB
  float* psum = (float*)(ws + 203423744ull);                    // 4 MB (512 x 2048)
  float* psq  = (float*)(ws + 207618048ull);                    // 4 MB
  float* chp  = (float*)(ws + 211812352ull);                    // 16 KB
  double* chpd = (double*)(ws + 211828736ull);                  // 8 KB

  float* out = (float*)d_out;

  // ---- q path (R1-verbatim, frozen) ----
  gemm_nt<<<dim3(4,128), 256, 0, stream>>>(x, qw, qb, bufY, C_, C_);
  col_stats_partial<<<512, 256, 0, stream>>>(bufY, C_, psum, psq);
  col_stats_final<<<2, 256, 0, stream>>>(psum, psq, C_, qg, qbe, chp);
  bnlif_mask<<<8192, 256, 0, stream>>>(bufY, chp, qmask);
  // ---- k path (R1-verbatim, frozen) ----
  gemm_nt<<<dim3(4,128), 256, 0, stream>>>(x, kw, kb, bufY, C_, C_);
  col_stats_partial<<<512, 256, 0, stream>>>(bufY, C_, psum, psq);
  col_stats_final<<<2, 256, 0, stream>>>(psum, psq, C_, kg, kbe, chp);
  bnlif_mask<<<8192, 256, 0, stream>>>(bufY, chp, kmask);
  // ---- v path (REDRAWN: f64-internal) ----
  gemm_nt_f64acc<<<dim3(8,256), 256, 0, stream>>>(x, vw, vb, bufY, C_, C_);
  col_stats_partial<<<512, 256, 0, stream>>>(bufY, C_, psum, psq);
  col_stats_final_f64<<<2, 256, 0, stream>>>(psum, psq, C_, vg, vbe, chpd);
  bn_apply_f64<<<2048, 256, 0, stream>>>(bufY, chpd, bufV);
  // ---- attention (REDRAWN: f64 PV accumulation) ----
  attn_kernel_f64<<<2048, 256, 0, stream>>>(qmask, kmask, bufV, bufO);
  // ---- projection + residual (REDRAWN: f64-internal) ----
  gemm_nt_f64acc<<<dim3(8,256), 256, 0, stream>>>(bufO, pw, pb, bufY, C_, C_);
  col_stats_partial<<<512, 256, 0, stream>>>(bufY, C_, psum, psq);
  col_stats_final_f64<<<2, 256, 0, stream>>>(psum, psq, C_, pg, pbe, chpd);
  bn_residual_f64<<<2048, 256, 0, stream>>>(bufY, chpd, x, bufO);
  // ---- MLP f1 (R1-verbatim) ----
  gemm_nt<<<dim3(16,128), 256, 0, stream>>>(bufO, f1w, f1b, bufY, HID_, C_);
  col_stats_partial<<<512, 256, 0, stream>>>(bufY, HID_, psum, psq);
  col_stats_final<<<8, 256, 0, stream>>>(psum, psq, HID_, f1g, f1be, chp);
  bnlif_inplace<<<dim3(8,4096), 256, 0, stream>>>(bufY, chp);
  // ---- MLP f2 (R1-verbatim) ----
  gemm_nt<<<dim3(4,128), 256, 0, stream>>>(bufY, f2w, f2b, bufV, C_, HID_);
  col_stats_partial<<<512, 256, 0, stream>>>(bufV, C_, psum, psq);
  col_stats_final<<<2, 256, 0, stream>>>(psum, psq, C_, f2g, f2be, chp);
  bnlif_final<<<dim3(2,4096), 256, 0, stream>>>(bufV, chp, bufO, out);
}